// Round 5
// baseline (26.703 us; speedup 1.0000x reference)
//
#include <hip/hip_runtime.h>
#include <hip/hip_bf16.h>

// NAM inference: B=16384 rows, F=64 features, U=64 units per FeatureNN.
// fnn[b,f] = sum_u clamp((x[b,f]-eb[f])*exp(w[f,u]),0,1)*lw[f,u] + lb[f]
// out[b]   = sum_f fnn[b,f] + bias
// I/O contract (verified over rounds 1-4): inputs fp32 in dict order;
// d_out is FP32, [out(16384) | fnn(16384x64 row-major)].

#define NB 16384
#define NF 64
#define NU 64

// Prep: transpose weights to u-major and pre-exponentiate, so the main
// kernel's per-u accesses for a wave's 8 features are 8 consecutive floats
// (-> wave-uniform scalar s_load broadcasts).
__global__ __launch_bounds__(256) void nam_prep(const float* __restrict__ exu_w,
                                                const float* __restrict__ lin_w,
                                                float* __restrict__ ewt,
                                                float* __restrict__ lwt) {
    int t = blockIdx.x * 256 + threadIdx.x;   // t = u*64 + f
    if (t < NF * NU) {
        int u = t >> 6;
        int f = t & 63;
        ewt[t] = __expf(exu_w[f * NU + u]);
        lwt[t] = lin_w[f * NU + u];
    }
}

// Main: 256 blocks x 512 threads. Each block owns 64 batch rows.
// lane (0..63) = row within block; wave (0..7) = feature group of 8.
// Weights are wave-uniform -> SGPR broadcast; x is 32B/lane vectorized.
__global__ __launch_bounds__(512) void nam_main(
    const float* __restrict__ x,
    const float* __restrict__ ewt,
    const float* __restrict__ lwt,
    const float* __restrict__ exu_b,
    const float* __restrict__ lin_b,
    const float* __restrict__ bias,
    float* __restrict__ out,
    float* __restrict__ fnn) {

    __shared__ float psum[8][64];

    const int lane = threadIdx.x & 63;
    const int wv = __builtin_amdgcn_readfirstlane(threadIdx.x >> 6); // force SGPR
    const int f0 = wv * 8;
    const int row = blockIdx.x * 64 + lane;

    // Load this lane's 8 x-values (32B contiguous per lane).
    const float* xr = x + (size_t)row * NF + f0;
    float4 xa = *(const float4*)(xr);
    float4 xb = *(const float4*)(xr + 4);
    float xv[8] = {xa.x, xa.y, xa.z, xa.w, xb.x, xb.y, xb.z, xb.w};
    float acc[8];
#pragma unroll
    for (int j = 0; j < 8; ++j) {
        xv[j] -= exu_b[f0 + j];   // hoist (x - eb) out of the u-loop
        acc[j] = 0.0f;
    }

    // 8 independent fmac chains; ew/lw are uniform scalar loads.
#pragma unroll 8
    for (int u = 0; u < NU; ++u) {
        const float* ew = ewt + (u << 6) + f0;
        const float* lw = lwt + (u << 6) + f0;
#pragma unroll
        for (int j = 0; j < 8; ++j) {
            float h = xv[j] * ew[j];
            h = __builtin_fminf(__builtin_fmaxf(h, 0.0f), 1.0f);  // -> v_med3_f32
            acc[j] = __builtin_fmaf(h, lw[j], acc[j]);
        }
    }

    // Epilogue: add lin_b, emit fnn (8 fp32 = two float4 stores/lane), row sum.
    float fo[8];
    float rs = 0.0f;
#pragma unroll
    for (int j = 0; j < 8; ++j) {
        fo[j] = acc[j] + lin_b[f0 + j];
        rs += fo[j];
    }
    float* fr = fnn + (size_t)row * NF + f0;   // (row*64+f0)*4B: f0*4=wv*32 -> 16B aligned
    *(float4*)(fr)     = make_float4(fo[0], fo[1], fo[2], fo[3]);
    *(float4*)(fr + 4) = make_float4(fo[4], fo[5], fo[6], fo[7]);

    psum[wv][lane] = rs;
    __syncthreads();
    if (wv == 0) {
        float s = bias[0];
#pragma unroll
        for (int w = 0; w < 8; ++w) s += psum[w][lane];
        out[row] = s;
    }
}

// Fallback (no workspace): fully scalar, fp32 out. One thread per (b,f).
__global__ __launch_bounds__(256) void nam_fnn_scalar(const float* __restrict__ x,
                                                      const float* __restrict__ exu_w,
                                                      const float* __restrict__ exu_b,
                                                      const float* __restrict__ lin_w,
                                                      const float* __restrict__ lin_b,
                                                      float* __restrict__ fnn) {
    int t = blockIdx.x * 256 + threadIdx.x;   // t = b*NF + f
    if (t >= NB * NF) return;
    int f = t & (NF - 1);
    float xv = x[t] - exu_b[f];
    float acc = 0.0f;
    for (int u = 0; u < NU; ++u) {
        float h = xv * __expf(exu_w[f * NU + u]);
        h = fminf(fmaxf(h, 0.0f), 1.0f);
        acc = fmaf(h, lin_w[f * NU + u], acc);
    }
    fnn[t] = acc + lin_b[f];
}

__global__ __launch_bounds__(256) void nam_out_scalar(const float* __restrict__ fnn,
                                                      const float* __restrict__ bias,
                                                      float* __restrict__ out) {
    int b = blockIdx.x * 256 + threadIdx.x;
    if (b >= NB) return;
    float s = bias[0];
    for (int f = 0; f < NF; ++f) s += fnn[(size_t)b * NF + f];
    out[b] = s;
}

extern "C" void kernel_launch(void* const* d_in, const int* in_sizes, int n_in,
                              void* d_out, int out_size, void* d_ws, size_t ws_size,
                              hipStream_t stream) {
    const float* x     = (const float*)d_in[0];
    const float* exu_w = (const float*)d_in[1];
    const float* exu_b = (const float*)d_in[2];
    const float* lin_w = (const float*)d_in[3];
    const float* lin_b = (const float*)d_in[4];
    const float* bias  = (const float*)d_in[5];

    float* out = (float*)d_out;
    float* fnn = out + NB;

    if (ws_size >= (size_t)2 * NF * NU * sizeof(float)) {
        float* ewt = (float*)d_ws;
        float* lwt = ewt + NF * NU;
        nam_prep<<<dim3((NF * NU + 255) / 256), dim3(256), 0, stream>>>(
            exu_w, lin_w, ewt, lwt);
        nam_main<<<dim3(NB / 64), dim3(512), 0, stream>>>(
            x, ewt, lwt, exu_b, lin_b, bias, out, fnn);
    } else {
        nam_fnn_scalar<<<dim3((NB * NF + 255) / 256), dim3(256), 0, stream>>>(
            x, exu_w, exu_b, lin_w, lin_b, fnn);
        nam_out_scalar<<<dim3((NB + 255) / 256), dim3(256), 0, stream>>>(
            fnn, bias, out);
    }
}

// Round 6
// 12.473 us; speedup vs baseline: 2.1409x; 2.1409x over previous
//
#include <hip/hip_runtime.h>
#include <hip/hip_bf16.h>

// NAM inference: B=16384 rows, F=64 features, U=64 units per FeatureNN.
// fnn[b,f] = sum_u clamp((x[b,f]-eb[f])*exp(w[f,u]),0,1)*lw[f,u] + lb[f]
// out[b]   = sum_f fnn[b,f] + bias
// I/O contract (HW-verified round 5): fp32 inputs, dict order;
// d_out fp32 = [out(16384) | fnn(16384x64 row-major)].
//
// Single fused kernel: per-block LDS staging of exp(exu_w), lin_w transposed
// to u-major (stride 68 -> 16B-aligned ds_read_b128 broadcasts), lane=row
// mapping so weight reads are wave-uniform, 8 independent fmac chains/lane.

#define NB 16384
#define NF 64
#define NU 64
#define LDP 68   // padded LDS row stride (floats): u*68+f0 is 16B-aligned

__global__ __launch_bounds__(512) void nam_fused(
    const float* __restrict__ x,
    const float* __restrict__ exu_w,
    const float* __restrict__ exu_b,
    const float* __restrict__ lin_b,
    const float* __restrict__ lin_w,
    const float* __restrict__ bias,
    float* __restrict__ out,
    float* __restrict__ fnn) {

    __shared__ float ews[NU * LDP];
    __shared__ float lws[NU * LDP];
    __shared__ float psum[8][64];

    const int t = threadIdx.x;
    const int lane = t & 63;
    const int wv = __builtin_amdgcn_readfirstlane(t >> 6);
    const int f0 = wv * 8;
    const int row = blockIdx.x * 64 + lane;

    // Issue this lane's x loads early (overlap HBM latency with staging).
    const float* xr = x + (size_t)row * NF + f0;
    float4 xa = *(const float4*)(xr);
    float4 xb = *(const float4*)(xr + 4);

    // Stage weights: transpose [f][u] -> LDS [u][f] (stride LDP), exp fused.
    {
        int g0 = t * 8;             // 8 consecutive source elements / thread
        int f = g0 >> 6;
        int u0 = g0 & 63;
        float4 a0 = *(const float4*)(exu_w + g0);
        float4 a1 = *(const float4*)(exu_w + g0 + 4);
        float4 b0 = *(const float4*)(lin_w + g0);
        float4 b1 = *(const float4*)(lin_w + g0 + 4);
        float av[8] = {a0.x, a0.y, a0.z, a0.w, a1.x, a1.y, a1.z, a1.w};
        float bv[8] = {b0.x, b0.y, b0.z, b0.w, b1.x, b1.y, b1.z, b1.w};
#pragma unroll
        for (int k = 0; k < 8; ++k) {
            ews[(u0 + k) * LDP + f] = __expf(av[k]);
            lws[(u0 + k) * LDP + f] = bv[k];
        }
    }

    float xv[8] = {xa.x, xa.y, xa.z, xa.w, xb.x, xb.y, xb.z, xb.w};
    float acc[8];
#pragma unroll
    for (int j = 0; j < 8; ++j) {
        xv[j] -= exu_b[f0 + j];     // hoist (x - eb) out of the u-loop
        acc[j] = 0.0f;
    }

    __syncthreads();

    // 64 units; weights broadcast from LDS (wave-uniform ds_read_b128 x4/u).
#pragma unroll 4
    for (int u = 0; u < NU; ++u) {
        const float* ew = &ews[u * LDP + f0];
        const float* lw = &lws[u * LDP + f0];
#pragma unroll
        for (int j = 0; j < 8; ++j) {
            float h = xv[j] * ew[j];
            h = __builtin_amdgcn_fmed3f(h, 0.0f, 1.0f);   // ReLU-1 in 1 inst
            acc[j] = __builtin_fmaf(h, lw[j], acc[j]);
        }
    }

    // Epilogue: + lin_b, write fnn (two float4/lane), block row-reduce for out.
    float fo[8];
    float rs = 0.0f;
#pragma unroll
    for (int j = 0; j < 8; ++j) {
        fo[j] = acc[j] + lin_b[f0 + j];
        rs += fo[j];
    }
    float* fr = fnn + (size_t)row * NF + f0;  // wv*32B -> 16B aligned
    *(float4*)(fr)     = make_float4(fo[0], fo[1], fo[2], fo[3]);
    *(float4*)(fr + 4) = make_float4(fo[4], fo[5], fo[6], fo[7]);

    psum[wv][lane] = rs;
    __syncthreads();
    if (wv == 0) {
        float s = bias[0];
#pragma unroll
        for (int w = 0; w < 8; ++w) s += psum[w][lane];
        out[row] = s;
    }
}

extern "C" void kernel_launch(void* const* d_in, const int* in_sizes, int n_in,
                              void* d_out, int out_size, void* d_ws, size_t ws_size,
                              hipStream_t stream) {
    const float* x     = (const float*)d_in[0];
    const float* exu_w = (const float*)d_in[1];
    const float* exu_b = (const float*)d_in[2];
    const float* lin_w = (const float*)d_in[3];
    const float* lin_b = (const float*)d_in[4];
    const float* bias  = (const float*)d_in[5];

    float* out = (float*)d_out;
    float* fnn = out + NB;

    nam_fused<<<dim3(NB / 64), dim3(512), 0, stream>>>(
        x, exu_w, exu_b, lin_b, lin_w, bias, out, fnn);
}